// Round 1
// baseline (370.848 us; speedup 1.0000x reference)
//
#include <hip/hip_runtime.h>
#include <math.h>

#define B_ 8
#define CI 128
#define CO 128
#define HH 64
#define WW 64
#define HW 4096
#define KK9 9

// ws layout (float offsets)
#define WS_XT   0u            // [8][4096][128]       4194304
#define WS_WT   4194304u      // [9][128][128]        147456
#define WS_OMP  4341760u      // [2][8][27][4096]     1769472
#define WS_Y    6111232u      // [8][128][4096]       4194304
#define WS_PS   10305536u     // [128][512]           65536
#define WS_PQ   10371072u     // [128][512]           65536
#define WS_SC   10436608u     // [128]
#define WS_SH   10436736u     // [128]

// ---------------- x NCHW -> NHWC transpose ----------------
__global__ __launch_bounds__(256) void k_xt(const float* __restrict__ x,
                                            float* __restrict__ xt) {
  __shared__ float tile[32][33];
  int hw0 = blockIdx.x * 32;
  int c0  = blockIdx.y * 32;
  int b   = blockIdx.z;
  int col = threadIdx.x & 31, row = threadIdx.x >> 5;  // row 0..7
  const float* xb = x + ((size_t)b * CI + c0) * HW + hw0;
#pragma unroll
  for (int i = 0; i < 32; i += 8)
    tile[row + i][col] = xb[(size_t)(row + i) * HW + col];
  __syncthreads();
  float* xtb = xt + ((size_t)b * HW + hw0) * CI + c0;
#pragma unroll
  for (int i = 0; i < 32; i += 8)
    xtb[(size_t)(row + i) * CI + col] = tile[col][row + i];
}

// ---------------- w [O][C][9] -> wt [9][C][O] ----------------
__global__ void k_wt(const float* __restrict__ w, float* __restrict__ wt) {
  int idx = blockIdx.x * 256 + threadIdx.x;
  if (idx < CO * CI * KK9) {
    int k = idx % 9;
    int c = (idx / 9) % CI;
    int o = idx / (9 * CI);
    wt[((size_t)k * CI + c) * CO + o] = w[idx];
  }
}

// ---------------- offset conv (27ch, 3x3, pad1), ci split in half ------------
__global__ __launch_bounds__(256) void k_off(const float* __restrict__ x,
                                             const float* __restrict__ ow,
                                             float* __restrict__ omp) {
  int t = threadIdx.x;
  int pix = blockIdx.x * 256 + t;
  int b = blockIdx.y, half = blockIdx.z;
  int h = pix >> 6, wx = pix & 63;
  float acc[27];
#pragma unroll
  for (int o = 0; o < 27; o++) acc[o] = 0.f;
  const float* xb = x + ((size_t)b * CI + half * 64) * HW;
  for (int ci = 0; ci < 64; ci++) {
    float xv[9];
#pragma unroll
    for (int dy = 0; dy < 3; dy++)
#pragma unroll
      for (int dx = 0; dx < 3; dx++) {
        int yy = h + dy - 1, xx = wx + dx - 1;
        bool v = (yy >= 0 && yy < HH && xx >= 0 && xx < WW);
        xv[dy * 3 + dx] = v ? xb[(size_t)ci * HW + yy * WW + xx] : 0.f;
      }
    const float* wr = ow + (size_t)(half * 64 + ci) * 9;  // + o*1152 + k
#pragma unroll
    for (int o = 0; o < 27; o++) {
#pragma unroll
      for (int k = 0; k < 9; k++)
        acc[o] += xv[k] * wr[(size_t)o * (CI * 9) + k];
    }
  }
  float* ob = omp + ((size_t)half * B_ + b) * 27 * HW + pix;
#pragma unroll
  for (int o = 0; o < 27; o++) ob[(size_t)o * HW] = acc[o];
}

// ---------------- main deformable GEMM + y + BN partials ----------------
// block: 128 o x 64 p (p = one image row). 256 threads: thread = (to,tp),
// o0=to*8, p0=tp*4, acc[8][4]. LDS: Ws[64c][128o] + Vs[64c][64p].
__global__ __launch_bounds__(256) void k_main(
    const float* __restrict__ xt, const float* __restrict__ wt,
    const float* __restrict__ omp, const float* __restrict__ off_b,
    const float* __restrict__ bias, float* __restrict__ y,
    float* __restrict__ ps, float* __restrict__ pq) {
  __shared__ float Ws[64 * 128];
  __shared__ float Vs[64 * 64];
  int t = threadIdx.x;
  int row = blockIdx.x, b = blockIdx.y;
  int to = t >> 4, tp = t & 15;
  int o0 = to * 8, p0 = tp * 4;
  int pixl = t & 63;  // staging pixel
  int cg = t >> 6;    // staging c-group (16 c per wave)
  float acc[8][4] = {};
  const float* ompb0 = omp + (size_t)b * 27 * HW + row * 64;
  const float* ompb1 = omp + ((size_t)B_ + b) * 27 * HW + row * 64;
  const float* xtb = xt + (size_t)b * HW * CI;

  for (int k = 0; k < 9; k++) {
    int ky = k / 3, kx = k % 3;
    float offy = ompb0[(2 * k) * HW + pixl] + ompb1[(2 * k) * HW + pixl] + off_b[2 * k];
    float offx = ompb0[(2 * k + 1) * HW + pixl] + ompb1[(2 * k + 1) * HW + pixl] + off_b[2 * k + 1];
    float mraw = ompb0[(18 + k) * HW + pixl] + ompb1[(18 + k) * HW + pixl] + off_b[18 + k];
    float m = 1.f / (1.f + __expf(-mraw));
    float py = offy + (float)(row - 1 + ky);
    float px = offx + (float)(pixl - 1 + kx);
    float y0f = floorf(py), x0f = floorf(px);
    float ly = py - y0f, lx = px - x0f;
    int iy0 = (int)y0f, ix0 = (int)x0f;
    int iy1 = iy0 + 1, ix1 = ix0 + 1;
    float w00 = (1.f - ly) * (1.f - lx) * m, w01 = (1.f - ly) * lx * m;
    float w10 = ly * (1.f - lx) * m, w11 = ly * lx * m;
    if (iy0 < 0 || iy0 > HH - 1) { w00 = 0.f; w01 = 0.f; }
    if (iy1 < 0 || iy1 > HH - 1) { w10 = 0.f; w11 = 0.f; }
    if (ix0 < 0 || ix0 > WW - 1) { w00 = 0.f; w10 = 0.f; }
    if (ix1 < 0 || ix1 > WW - 1) { w01 = 0.f; w11 = 0.f; }
    int cy0 = min(max(iy0, 0), HH - 1), cy1 = min(max(iy1, 0), HH - 1);
    int cx0 = min(max(ix0, 0), WW - 1), cx1 = min(max(ix1, 0), WW - 1);
    const float* r00 = xtb + ((size_t)cy0 * WW + cx0) * CI;
    const float* r01 = xtb + ((size_t)cy0 * WW + cx1) * CI;
    const float* r10 = xtb + ((size_t)cy1 * WW + cx0) * CI;
    const float* r11 = xtb + ((size_t)cy1 * WW + cx1) * CI;

    for (int cc = 0; cc < 2; cc++) {
      int c0 = cc * 64;
      __syncthreads();
      // stage Ws: [64c][128o], coalesced float4
      const float4* wsrc = (const float4*)(wt + ((size_t)k * CI + c0) * CO);
      float4* wdst = (float4*)Ws;
#pragma unroll
      for (int j = 0; j < 8; j++) wdst[t + j * 256] = wsrc[t + j * 256];
      // stage Vs: this thread fills 16 c for pixel pixl
#pragma unroll
      for (int j = 0; j < 4; j++) {
        int cb = c0 + cg * 16 + j * 4;
        float4 v00 = *(const float4*)(r00 + cb);
        float4 v01 = *(const float4*)(r01 + cb);
        float4 v10 = *(const float4*)(r10 + cb);
        float4 v11 = *(const float4*)(r11 + cb);
        int cl = cg * 16 + j * 4;
        Vs[(cl + 0) * 64 + pixl] = w00 * v00.x + w01 * v01.x + w10 * v10.x + w11 * v11.x;
        Vs[(cl + 1) * 64 + pixl] = w00 * v00.y + w01 * v01.y + w10 * v10.y + w11 * v11.y;
        Vs[(cl + 2) * 64 + pixl] = w00 * v00.z + w01 * v01.z + w10 * v10.z + w11 * v11.z;
        Vs[(cl + 3) * 64 + pixl] = w00 * v00.w + w01 * v01.w + w10 * v10.w + w11 * v11.w;
      }
      __syncthreads();
#pragma unroll 4
      for (int c = 0; c < 64; c++) {
        float4 wa = *(const float4*)(Ws + c * 128 + o0);
        float4 wb = *(const float4*)(Ws + c * 128 + o0 + 4);
        float4 vf = *(const float4*)(Vs + c * 64 + p0);
        float wv[8] = {wa.x, wa.y, wa.z, wa.w, wb.x, wb.y, wb.z, wb.w};
        float vv[4] = {vf.x, vf.y, vf.z, vf.w};
#pragma unroll
        for (int i = 0; i < 8; i++)
#pragma unroll
          for (int j = 0; j < 4; j++) acc[i][j] += wv[i] * vv[j];
      }
    }
  }
  // epilogue: bias, store y, BN partials
  int blk = b * 64 + row;
#pragma unroll
  for (int i = 0; i < 8; i++) {
    float bb = bias[o0 + i];
    float4 r;
    r.x = acc[i][0] + bb; r.y = acc[i][1] + bb;
    r.z = acc[i][2] + bb; r.w = acc[i][3] + bb;
    *(float4*)(y + ((size_t)b * CO + o0 + i) * HW + row * 64 + p0) = r;
    float s = r.x + r.y + r.z + r.w;
    float q = r.x * r.x + r.y * r.y + r.z * r.z + r.w * r.w;
#pragma unroll
    for (int off = 8; off >= 1; off >>= 1) {
      s += __shfl_down(s, off, 16);
      q += __shfl_down(q, off, 16);
    }
    if (tp == 0) {
      ps[(size_t)(o0 + i) * 512 + blk] = s;
      pq[(size_t)(o0 + i) * 512 + blk] = q;
    }
  }
}

// ---------------- BN stats: 512 partials per channel -> scale/shift ---------
__global__ __launch_bounds__(256) void k_stats(const float* __restrict__ ps,
                                               const float* __restrict__ pq,
                                               const float* __restrict__ gamma,
                                               const float* __restrict__ beta,
                                               float* __restrict__ sc,
                                               float* __restrict__ sh) {
  int o = blockIdx.x, t = threadIdx.x;
  float s = ps[(size_t)o * 512 + t] + ps[(size_t)o * 512 + 256 + t];
  float q = pq[(size_t)o * 512 + t] + pq[(size_t)o * 512 + 256 + t];
#pragma unroll
  for (int off = 32; off >= 1; off >>= 1) {
    s += __shfl_down(s, off, 64);
    q += __shfl_down(q, off, 64);
  }
  __shared__ float bs[4], bq[4];
  if ((t & 63) == 0) { bs[t >> 6] = s; bq[t >> 6] = q; }
  __syncthreads();
  if (t == 0) {
    s = bs[0] + bs[1] + bs[2] + bs[3];
    q = bq[0] + bq[1] + bq[2] + bq[3];
    float mean = s * (1.f / 32768.f);
    float var = q * (1.f / 32768.f) - mean * mean;
    float scale = gamma[o] * rsqrtf(var + 1e-5f);
    sc[o] = scale;
    sh[o] = beta[o] - mean * scale;
  }
}

// ---------------- normalize + ReLU ----------------
__global__ __launch_bounds__(256) void k_norm(const float* __restrict__ y,
                                              const float* __restrict__ sc,
                                              const float* __restrict__ sh,
                                              float* __restrict__ out) {
  int i4 = blockIdx.x * 256 + threadIdx.x;  // float4 index over 1048576
  int o = (i4 >> 10) & 127;
  float scale = sc[o], shift = sh[o];
  float4 v = ((const float4*)y)[i4];
  float4 r;
  r.x = fmaxf(v.x * scale + shift, 0.f);
  r.y = fmaxf(v.y * scale + shift, 0.f);
  r.z = fmaxf(v.z * scale + shift, 0.f);
  r.w = fmaxf(v.w * scale + shift, 0.f);
  ((float4*)out)[i4] = r;
}

extern "C" void kernel_launch(void* const* d_in, const int* in_sizes, int n_in,
                              void* d_out, int out_size, void* d_ws, size_t ws_size,
                              hipStream_t stream) {
  const float* x     = (const float*)d_in[0];
  const float* off_w = (const float*)d_in[1];
  const float* off_b = (const float*)d_in[2];
  const float* w     = (const float*)d_in[3];
  const float* bias  = (const float*)d_in[4];
  const float* gamma = (const float*)d_in[5];
  const float* beta  = (const float*)d_in[6];
  float* out = (float*)d_out;
  float* ws = (float*)d_ws;

  float* xt  = ws + WS_XT;
  float* wt  = ws + WS_WT;
  float* omp = ws + WS_OMP;
  float* y   = ws + WS_Y;
  float* ps  = ws + WS_PS;
  float* pq  = ws + WS_PQ;
  float* sc  = ws + WS_SC;
  float* sh  = ws + WS_SH;

  k_wt<<<576, 256, 0, stream>>>(w, wt);
  k_xt<<<dim3(128, 4, 8), 256, 0, stream>>>(x, xt);
  k_off<<<dim3(16, 8, 2), 256, 0, stream>>>(x, off_w, omp);
  k_main<<<dim3(64, 8), 256, 0, stream>>>(xt, wt, omp, off_b, bias, y, ps, pq);
  k_stats<<<128, 256, 0, stream>>>(ps, pq, gamma, beta, sc, sh);
  k_norm<<<4096, 256, 0, stream>>>(y, sc, sh, out);
}

// Round 3
// 182.828 us; speedup vs baseline: 2.0284x; 2.0284x over previous
//
#include <hip/hip_runtime.h>
#include <hip/hip_bf16.h>
#include <math.h>

#define B_ 8
#define HH 64
#define WW 64
#define HW 4096
#define LDV 136  // Vl row stride in bf16 elems (128 + 8 pad, keeps 16B align)

typedef __bf16 bf16x8 __attribute__((ext_vector_type(8)));
typedef float floatx4 __attribute__((ext_vector_type(4)));
typedef unsigned int uint4a __attribute__((ext_vector_type(4)));

// ws layout (byte offsets)
#define WS_Y    0u          // float y[8][128][4096]      16777216 B
#define WS_SC   16777216u   // float[128]
#define WS_SH   16778240u   // float[128]
#define WS_XTB  16779264u   // bf16 xtb[8][4096][128]      8388608 B
#define WS_WTB  25167872u   // bf16 wtb[9][128][128]        294912 B
#define WS_OWB  25462784u   // bf16 owb[9][32][128]          73728 B

static __device__ inline ushort f2bf(float f) {
  __hip_bfloat16 h = __float2bfloat16(f);
  return __builtin_bit_cast(ushort, h);
}
static __device__ inline float lo16(unsigned int u) { return __builtin_bit_cast(float, u << 16); }
static __device__ inline float hi16(unsigned int u) { return __builtin_bit_cast(float, u & 0xffff0000u); }

// ---------------- weights prep: wtb[9][128][128], owb[9][32][128] (bf16) -----
__global__ __launch_bounds__(256) void k_prepw(const float* __restrict__ w,
                                               const float* __restrict__ ow,
                                               ushort* __restrict__ wtb,
                                               ushort* __restrict__ owb) {
  int idx = blockIdx.x * 256 + threadIdx.x;
  if (idx < 147456) {
    int c = idx & 127, o = (idx >> 7) & 127, k = idx >> 14;
    wtb[idx] = f2bf(w[(o * 128 + c) * 9 + k]);
  } else {
    int j = idx - 147456;
    if (j < 36864) {
      int c = j & 127, o = (j >> 7) & 31, k = j >> 12;
      float v = (o < 27) ? ow[(o * 128 + c) * 9 + k] : 0.f;
      owb[j] = f2bf(v);
    }
  }
}

// ---------------- x NCHW fp32 -> NHWC bf16 ----------------
__global__ __launch_bounds__(256) void k_xt(const float* __restrict__ x,
                                            ushort* __restrict__ xtb) {
  __shared__ float tile[32][33];
  int hw0 = blockIdx.x * 32;
  int c0 = blockIdx.y * 32;
  int b = blockIdx.z;
  int col = threadIdx.x & 31, row = threadIdx.x >> 5;  // col=hw, row=c 0..7
  const float* xb = x + ((size_t)b * 128 + c0) * HW + hw0;
#pragma unroll
  for (int i = 0; i < 32; i += 8)
    tile[row + i][col] = xb[(size_t)(row + i) * HW + col];
  __syncthreads();
  int cpair = threadIdx.x & 15, hwi = threadIdx.x >> 4;  // hwi 0..15
  ushort* xo = xtb + ((size_t)b * HW + hw0) * 128 + c0;
#pragma unroll
  for (int i = 0; i < 32; i += 16) {
    int hw = hwi + i;
    unsigned int v = (unsigned int)f2bf(tile[2 * cpair][hw]) |
                     ((unsigned int)f2bf(tile[2 * cpair + 1][hw]) << 16);
    *(unsigned int*)(&xo[(size_t)hw * 128 + 2 * cpair]) = v;
  }
}

// ---------------- fused offset-conv + deformable GEMM ----------------
// grid (64 rows, 8 batch), 256 threads = 4 waves.
__global__ __launch_bounds__(256) void k_main(
    const ushort* __restrict__ xtb, const ushort* __restrict__ wtb,
    const ushort* __restrict__ owb, const float* __restrict__ off_b,
    const float* __restrict__ bias, float* __restrict__ y) {
  __shared__ ushort Vl[64 * LDV];  // 17408 B
  __shared__ float omL[27 * 64];   // 6912 B
  int t = threadIdx.x;
  int lane = t & 63, wv = t >> 6;
  int li = lane & 15, quad = lane >> 4;
  int row = blockIdx.x, b = blockIdx.y;
  const ushort* xb = xtb + (size_t)b * HW * 128;
  int sp = lane, scg = wv;  // staging pixel / c-group (32c)

  // ===== phase 1: offset conv -> omL[27][64] =====
  floatx4 oacc[2];
  oacc[0] = (floatx4){0.f, 0.f, 0.f, 0.f};
  oacc[1] = (floatx4){0.f, 0.f, 0.f, 0.f};
  for (int k = 0; k < 9; ++k) {
    int ky = k / 3, kx = k % 3;
    int ry = row - 1 + ky;
    int col = sp - 1 + kx;
    bool v = (ry >= 0 && ry < HH && col >= 0 && col < WW);
    const uint4a* src = (const uint4a*)(xb + ((size_t)(ry * WW + col) * 128 + scg * 32));
    __syncthreads();
#pragma unroll
    for (int j = 0; j < 4; ++j) {
      uint4a d = (uint4a){0u, 0u, 0u, 0u};
      if (v) d = src[j];
      *(uint4a*)(&Vl[sp * LDV + scg * 32 + j * 8]) = d;
    }
    __syncthreads();
#pragma unroll
    for (int ks = 0; ks < 4; ++ks) {
      bf16x8 bfrag = __builtin_bit_cast(bf16x8,
          *(const uint4a*)(&Vl[(wv * 16 + li) * LDV + ks * 32 + quad * 8]));
#pragma unroll
      for (int ot = 0; ot < 2; ++ot) {
        bf16x8 afrag = __builtin_bit_cast(bf16x8,
            *(const uint4a*)(&owb[(size_t)(k * 32 + ot * 16 + li) * 128 + ks * 32 + quad * 8]));
        oacc[ot] = __builtin_amdgcn_mfma_f32_16x16x32_bf16(afrag, bfrag, oacc[ot], 0, 0, 0);
      }
    }
  }
  __syncthreads();
#pragma unroll
  for (int ot = 0; ot < 2; ++ot)
#pragma unroll
    for (int r = 0; r < 4; ++r) {
      int o = ot * 16 + quad * 4 + r;
      if (o < 27) omL[o * 64 + wv * 16 + li] = oacc[ot][r] + off_b[o];
    }
  __syncthreads();

  // ===== phase 2: deformable sampling + main GEMM =====
  int oh = wv & 1, ph = wv >> 1;  // wave tile: o-half (64), p-half (32)
  floatx4 macc[4][2];
#pragma unroll
  for (int i = 0; i < 4; ++i) {
    macc[i][0] = (floatx4){0.f, 0.f, 0.f, 0.f};
    macc[i][1] = (floatx4){0.f, 0.f, 0.f, 0.f};
  }
  for (int k = 0; k < 9; ++k) {
    int ky = k / 3, kx = k % 3;
    float offy = omL[(2 * k) * 64 + sp];
    float offx = omL[(2 * k + 1) * 64 + sp];
    float mraw = omL[(18 + k) * 64 + sp];
    float m = 1.f / (1.f + __expf(-mraw));
    float py = offy + (float)(row - 1 + ky);
    float px = offx + (float)(sp - 1 + kx);
    float y0f = floorf(py), x0f = floorf(px);
    float ly = py - y0f, lx = px - x0f;
    int iy0 = (int)y0f, ix0 = (int)x0f;
    int iy1 = iy0 + 1, ix1 = ix0 + 1;
    float w00 = (1.f - ly) * (1.f - lx) * m, w01 = (1.f - ly) * lx * m;
    float w10 = ly * (1.f - lx) * m, w11 = ly * lx * m;
    if (iy0 < 0 || iy0 > HH - 1) { w00 = 0.f; w01 = 0.f; }
    if (iy1 < 0 || iy1 > HH - 1) { w10 = 0.f; w11 = 0.f; }
    if (ix0 < 0 || ix0 > WW - 1) { w00 = 0.f; w10 = 0.f; }
    if (ix1 < 0 || ix1 > WW - 1) { w01 = 0.f; w11 = 0.f; }
    int cy0 = min(max(iy0, 0), HH - 1), cy1 = min(max(iy1, 0), HH - 1);
    int cx0 = min(max(ix0, 0), WW - 1), cx1 = min(max(ix1, 0), WW - 1);
    const uint4a* r00 = (const uint4a*)(xb + ((size_t)(cy0 * WW + cx0) * 128 + scg * 32));
    const uint4a* r01 = (const uint4a*)(xb + ((size_t)(cy0 * WW + cx1) * 128 + scg * 32));
    const uint4a* r10 = (const uint4a*)(xb + ((size_t)(cy1 * WW + cx0) * 128 + scg * 32));
    const uint4a* r11 = (const uint4a*)(xb + ((size_t)(cy1 * WW + cx1) * 128 + scg * 32));
    __syncthreads();  // previous iteration's MFMA done reading Vl
#pragma unroll
    for (int j = 0; j < 4; ++j) {
      uint4a u00 = r00[j], u01 = r01[j], u10 = r10[j], u11 = r11[j];
      uint4a out;
#pragma unroll
      for (int e = 0; e < 4; ++e) {
        float rlo = w00 * lo16(u00[e]) + w01 * lo16(u01[e]) +
                    w10 * lo16(u10[e]) + w11 * lo16(u11[e]);
        float rhi = w00 * hi16(u00[e]) + w01 * hi16(u01[e]) +
                    w10 * hi16(u10[e]) + w11 * hi16(u11[e]);
        out[e] = (unsigned int)f2bf(rlo) | ((unsigned int)f2bf(rhi) << 16);
      }
      *(uint4a*)(&Vl[sp * LDV + scg * 32 + j * 8]) = out;
    }
    __syncthreads();
#pragma unroll
    for (int ks = 0; ks < 4; ++ks) {
      bf16x8 bf0 = __builtin_bit_cast(bf16x8,
          *(const uint4a*)(&Vl[(ph * 32 + li) * LDV + ks * 32 + quad * 8]));
      bf16x8 bf1 = __builtin_bit_cast(bf16x8,
          *(const uint4a*)(&Vl[(ph * 32 + 16 + li) * LDV + ks * 32 + quad * 8]));
#pragma unroll
      for (int ot = 0; ot < 4; ++ot) {
        bf16x8 af = __builtin_bit_cast(bf16x8,
            *(const uint4a*)(&wtb[((size_t)k * 128 + oh * 64 + ot * 16 + li) * 128 + ks * 32 + quad * 8]));
        macc[ot][0] = __builtin_amdgcn_mfma_f32_16x16x32_bf16(af, bf0, macc[ot][0], 0, 0, 0);
        macc[ot][1] = __builtin_amdgcn_mfma_f32_16x16x32_bf16(af, bf1, macc[ot][1], 0, 0, 0);
      }
    }
  }
  // ===== epilogue: bias + y store =====
#pragma unroll
  for (int ot = 0; ot < 4; ++ot)
#pragma unroll
    for (int pt = 0; pt < 2; ++pt)
#pragma unroll
      for (int r = 0; r < 4; ++r) {
        int o = oh * 64 + ot * 16 + quad * 4 + r;
        int p = ph * 32 + pt * 16 + li;
        float val = macc[ot][pt][r] + bias[o];
        y[((size_t)(b * 128 + o)) * HW + row * 64 + p] = val;
      }
}

// ---------------- BN stats from y ----------------
__global__ __launch_bounds__(256) void k_stats(const float* __restrict__ y,
                                               const float* __restrict__ gamma,
                                               const float* __restrict__ beta,
                                               float* __restrict__ sc,
                                               float* __restrict__ sh) {
  int o = blockIdx.x, t = threadIdx.x;
  float s = 0.f, q = 0.f;
  for (int b = 0; b < 8; ++b) {
    const float4* yb = (const float4*)(y + ((size_t)(b * 128 + o)) * HW);
#pragma unroll
    for (int i = 0; i < 4; ++i) {
      float4 v = yb[t + i * 256];
      s += v.x + v.y + v.z + v.w;
      q += v.x * v.x + v.y * v.y + v.z * v.z + v.w * v.w;
    }
  }
#pragma unroll
  for (int off = 32; off >= 1; off >>= 1) {
    s += __shfl_down(s, off, 64);
    q += __shfl_down(q, off, 64);
  }
  __shared__ float bs[4], bq[4];
  if ((t & 63) == 0) { bs[t >> 6] = s; bq[t >> 6] = q; }
  __syncthreads();
  if (t == 0) {
    s = bs[0] + bs[1] + bs[2] + bs[3];
    q = bq[0] + bq[1] + bq[2] + bq[3];
    float mean = s * (1.f / 32768.f);
    float var = q * (1.f / 32768.f) - mean * mean;
    float scale = gamma[o] * rsqrtf(var + 1e-5f);
    sc[o] = scale;
    sh[o] = beta[o] - mean * scale;
  }
}

// ---------------- normalize + ReLU ----------------
__global__ __launch_bounds__(256) void k_norm(const float* __restrict__ y,
                                              const float* __restrict__ sc,
                                              const float* __restrict__ sh,
                                              float* __restrict__ out) {
  int i4 = blockIdx.x * 256 + threadIdx.x;
  int o = (i4 >> 10) & 127;
  float scale = sc[o], shift = sh[o];
  float4 v = ((const float4*)y)[i4];
  float4 r;
  r.x = fmaxf(v.x * scale + shift, 0.f);
  r.y = fmaxf(v.y * scale + shift, 0.f);
  r.z = fmaxf(v.z * scale + shift, 0.f);
  r.w = fmaxf(v.w * scale + shift, 0.f);
  ((float4*)out)[i4] = r;
}

extern "C" void kernel_launch(void* const* d_in, const int* in_sizes, int n_in,
                              void* d_out, int out_size, void* d_ws, size_t ws_size,
                              hipStream_t stream) {
  const float* x     = (const float*)d_in[0];
  const float* off_w = (const float*)d_in[1];
  const float* off_b = (const float*)d_in[2];
  const float* w     = (const float*)d_in[3];
  const float* bias  = (const float*)d_in[4];
  const float* gamma = (const float*)d_in[5];
  const float* beta  = (const float*)d_in[6];
  float* out = (float*)d_out;
  char* ws = (char*)d_ws;

  float* y   = (float*)(ws + WS_Y);
  float* sc  = (float*)(ws + WS_SC);
  float* sh  = (float*)(ws + WS_SH);
  ushort* xtb = (ushort*)(ws + WS_XTB);
  ushort* wtb = (ushort*)(ws + WS_WTB);
  ushort* owb = (ushort*)(ws + WS_OWB);

  k_prepw<<<720, 256, 0, stream>>>(w, off_w, wtb, owb);
  k_xt<<<dim3(128, 4, 8), 256, 0, stream>>>(x, xtb);
  k_main<<<dim3(64, 8), 256, 0, stream>>>(xtb, wtb, owb, off_b, bias, y);
  k_stats<<<128, 256, 0, stream>>>(y, gamma, beta, sc, sh);
  k_norm<<<4096, 256, 0, stream>>>(y, sc, sh, out);
}